// Round 3
// baseline (1367.092 us; speedup 1.0000x reference)
//
#include <hip/hip_runtime.h>
#include <cstdint>
#include <cstddef>

typedef _Float16 h2 __attribute__((ext_vector_type(2)));

__device__ __forceinline__ float sigf(float x) { return 1.0f / (1.0f + __expf(-x)); }
__device__ __forceinline__ float tanhfast(float x) {
  float e = __expf(-2.0f * fabsf(x));
  float t = (1.0f - e) / (1.0f + e);
  return copysignf(t, x);
}
__device__ __forceinline__ h2 cvt2(float a, float b) {
  h2 r; r.x = (_Float16)a; r.y = (_Float16)b; return r;
}
__device__ __forceinline__ h2 bch2(unsigned int u) { return __builtin_bit_cast(h2, u); }
__device__ __forceinline__ unsigned int bcu(h2 v) { return __builtin_bit_cast(unsigned int, v); }

__device__ __forceinline__ float fdot2f(h2 a, h2 b, float c) {
#if __has_builtin(__builtin_amdgcn_fdot2)
  return __builtin_amdgcn_fdot2(a, b, c, false);
#else
  return fmaf((float)a.x, (float)b.x, fmaf((float)a.y, (float)b.y, c));
#endif
}

// ---------------- part encoder ----------------
__global__ void part_encoder(const float* __restrict__ parts, const float* __restrict__ Wpe1,
                             const float* __restrict__ bpe1, const float* __restrict__ Wpe2,
                             const float* __restrict__ bpe2, const float* __restrict__ pos,
                             float* __restrict__ x) {
  __shared__ float prow[16];
  __shared__ float pe1[128];
  int row = blockIdx.x;
  int s = row & 255;
  int tid = threadIdx.x;  // 128
  if (tid < 16) prow[tid] = parts[row * 16 + tid];
  __syncthreads();
  float a = bpe1[tid];
#pragma unroll
  for (int k = 0; k < 16; ++k) a = fmaf(prow[k], Wpe1[tid * 16 + k], a);
  pe1[tid] = fmaxf(a, 0.0f);
  __syncthreads();
  float a2 = bpe2[tid];
  for (int k = 0; k < 128; ++k) a2 = fmaf(pe1[k], Wpe2[tid * 128 + k], a2);
  x[(size_t)row * 256 + tid] = a2;
  if (tid < 64) {
    x[(size_t)row * 256 + 128 + tid] = pos[s * 64 + tid];
    x[(size_t)row * 256 + 192 + tid] = 0.0f;
  }
}

// ---------------- generic f32 GEMM ----------------
template <int ACT>
__global__ __launch_bounds__(256) void gemm_f32(
    const float* __restrict__ A, const float* __restrict__ Wt,
    const float* __restrict__ bias1, const float* __restrict__ bias2,
    float* __restrict__ C, int N, int K) {
  __shared__ float As[16][68];
  __shared__ float Ws[16][68];
  int tid = threadIdx.x;
  int tx = tid & 15, ty = tid >> 4;
  int m0 = blockIdx.y * 64, n0 = blockIdx.x * 64;
  int mm = tid >> 2, c4 = (tid & 3) * 4;
  float acc[4][4] = {};
  for (int k0 = 0; k0 < K; k0 += 16) {
    float4 av = *(const float4*)&A[(size_t)(m0 + mm) * K + k0 + c4];
    float4 wv = *(const float4*)&Wt[(size_t)(n0 + mm) * K + k0 + c4];
    As[c4 + 0][mm] = av.x; As[c4 + 1][mm] = av.y; As[c4 + 2][mm] = av.z; As[c4 + 3][mm] = av.w;
    Ws[c4 + 0][mm] = wv.x; Ws[c4 + 1][mm] = wv.y; Ws[c4 + 2][mm] = wv.z; Ws[c4 + 3][mm] = wv.w;
    __syncthreads();
#pragma unroll
    for (int kk = 0; kk < 16; ++kk) {
      float4 a = *(const float4*)&As[kk][ty * 4];
      float4 w = *(const float4*)&Ws[kk][tx * 4];
      float aa[4] = {a.x, a.y, a.z, a.w};
      float ww[4] = {w.x, w.y, w.z, w.w};
#pragma unroll
      for (int i = 0; i < 4; ++i)
#pragma unroll
        for (int j = 0; j < 4; ++j) acc[i][j] = fmaf(aa[i], ww[j], acc[i][j]);
    }
    __syncthreads();
  }
#pragma unroll
  for (int i = 0; i < 4; ++i) {
    int m = m0 + ty * 4 + i;
    float4 o4;
    float* po = (float*)&o4;
#pragma unroll
    for (int j = 0; j < 4; ++j) {
      int n = n0 + tx * 4 + j;
      float v = acc[i][j] + bias1[n] + (bias2 ? bias2[n] : 0.0f);
      if (ACT == 1) v = fmaxf(v, 0.0f);
      po[j] = v;
    }
    *(float4*)&C[(size_t)m * N + n0 + tx * 4] = o4;
  }
}

// ---------------- attention ----------------
__global__ void attn_kernel(const float* __restrict__ qkv, float* __restrict__ attout) {
  extern __shared__ float sm[];
  float* kl = sm;
  float* ql = sm + 256 * 33;
  float* sc = sm + 256 * 33 + 32 * 33;
  int qt = blockIdx.x, h = blockIdx.y, b = blockIdx.z;
  int tid = threadIdx.x;  // 256
  {
    int j = tid;
    const float* src = qkv + (size_t)(b * 256 + j) * 768 + 256 + h * 32;
#pragma unroll
    for (int d = 0; d < 32; d += 4) {
      float4 v = *(const float4*)(src + d);
      kl[j * 33 + d] = v.x; kl[j * 33 + d + 1] = v.y; kl[j * 33 + d + 2] = v.z; kl[j * 33 + d + 3] = v.w;
    }
  }
  {
    int i = tid >> 3, d4 = (tid & 7) * 4;
    const float* src = qkv + (size_t)(b * 256 + qt * 32 + i) * 768 + h * 32;
    float4 v = *(const float4*)(src + d4);
    ql[i * 33 + d4] = v.x; ql[i * 33 + d4 + 1] = v.y; ql[i * 33 + d4 + 2] = v.z; ql[i * 33 + d4 + 3] = v.w;
  }
  __syncthreads();
  int i = tid >> 3, c = tid & 7;
  const float scale = 0.17677669529663687f;
  float sv[32];
  float mx = -1e30f;
  for (int jj = 0; jj < 32; ++jj) {
    int j = jj * 8 + c;
    float s = 0.0f;
#pragma unroll
    for (int d = 0; d < 32; ++d) s = fmaf(ql[i * 33 + d], kl[j * 33 + d], s);
    s *= scale;
    sv[jj] = s;
    mx = fmaxf(mx, s);
  }
  mx = fmaxf(mx, __shfl_xor(mx, 1));
  mx = fmaxf(mx, __shfl_xor(mx, 2));
  mx = fmaxf(mx, __shfl_xor(mx, 4));
  float sum = 0.0f;
  for (int jj = 0; jj < 32; ++jj) {
    float p = __expf(sv[jj] - mx);
    sc[i * 257 + jj * 8 + c] = p;
    sum += p;
  }
  sum += __shfl_xor(sum, 1);
  sum += __shfl_xor(sum, 2);
  sum += __shfl_xor(sum, 4);
  float inv = 1.0f / sum;
  __syncthreads();
  float a0 = 0, a1 = 0, a2 = 0, a3 = 0;
  int d0 = c * 4;
  const float* vbase = qkv + 512 + h * 32 + d0;
  for (int j = 0; j < 256; ++j) {
    float p = sc[i * 257 + j];
    float4 v = *(const float4*)(vbase + (size_t)(b * 256 + j) * 768);
    a0 = fmaf(p, v.x, a0); a1 = fmaf(p, v.y, a1); a2 = fmaf(p, v.z, a2); a3 = fmaf(p, v.w, a3);
  }
  int orow = b * 256 + qt * 32 + i;
  float4 o4 = {a0 * inv, a1 * inv, a2 * inv, a3 * inv};
  *(float4*)&attout[(size_t)orow * 256 + h * 32 + d0] = o4;
}

// ---------------- LayerNorm(x + o) ----------------
__global__ void ln_residual(float* __restrict__ x, const float* __restrict__ o,
                            const float* __restrict__ g, const float* __restrict__ bt) {
  int row = blockIdx.x, tid = threadIdx.x;  // 256
  float e = x[(size_t)row * 256 + tid] + o[(size_t)row * 256 + tid];
  float s = e, q = e * e;
#pragma unroll
  for (int off = 32; off >= 1; off >>= 1) {
    s += __shfl_xor(s, off);
    q += __shfl_xor(q, off);
  }
  __shared__ float ps[4], pq[4];
  int wid = tid >> 6, lane = tid & 63;
  if (lane == 0) { ps[wid] = s; pq[wid] = q; }
  __syncthreads();
  float St = ps[0] + ps[1] + ps[2] + ps[3];
  float Qt = pq[0] + pq[1] + pq[2] + pq[3];
  float mean = St * (1.0f / 256.0f);
  float var = Qt * (1.0f / 256.0f) - mean * mean;
  float y = (e - mean) * rsqrtf(var + 1e-5f) * g[tid] + bt[tid];
  x[(size_t)row * 256 + tid] = y;
}

// ---------------- gather dec_in ----------------
__global__ void gather_dec_in(const float* __restrict__ enc, const int* __restrict__ ts,
                              float* __restrict__ dec_in) {
  int bx = blockIdx.x;
  int t = bx >> 3, b = bx & 7;
  int tid = threadIdx.x;  // 64
  float4 v = {0.0f, 0.0f, 0.0f, 0.0f};
  if (t > 0) {
    int sidx = ts[b * 256 + t - 1];
    v = *(const float4*)&enc[((size_t)(b * 256 + sidx)) * 256 + tid * 4];
  }
  *(float4*)&dec_in[(size_t)bx * 256 + tid * 4] = v;
}

// ---------------- LSTM scan: 1 block/batch, 256 thr, thread j owns gate rows ----
// {j, j+256, j+512, j+768} = (i,f,g,o) for hidden unit j. c-update thread-local.
// Whh cols 0..191 in VGPRs (4 x 96 h2 = 384 VGPRs), cols 192..255 in LDS
// (XOR-swizzled [1024][8] uint4 = 128 KB). One barrier per step.
#define STAGE_ROW(WARR, R)                                                        \
  {                                                                               \
    const float4* s_ = (const float4*)(Whh + (size_t)(R) * 256);                  \
    _Pragma("unroll") for (int k = 0; k < 48; ++k) {                              \
      float4 v = s_[k];                                                           \
      WARR[2 * k] = cvt2(v.x, v.y);                                               \
      WARR[2 * k + 1] = cvt2(v.z, v.w);                                           \
    }                                                                             \
    _Pragma("unroll") for (int cb = 0; cb < 8; ++cb) {                            \
      float4 v0 = s_[48 + 2 * cb], v1 = s_[48 + 2 * cb + 1];                      \
      uint4 u;                                                                    \
      u.x = bcu(cvt2(v0.x, v0.y)); u.y = bcu(cvt2(v0.z, v0.w));                   \
      u.z = bcu(cvt2(v1.x, v1.y)); u.w = bcu(cvt2(v1.z, v1.w));                   \
      wl[(size_t)(R) * 8 + (cb ^ ((R) & 7))] = u;                                 \
    }                                                                             \
  }

__global__ __attribute__((amdgpu_flat_work_group_size(256, 256), amdgpu_waves_per_eu(1, 1)))
void lstm_scan(const float* __restrict__ Xw, const float* __restrict__ Whh,
               float* __restrict__ dec_out) {
  extern __shared__ char smem[];
  uint4* wl = (uint4*)smem;                 // [1024][8] uint4, swizzled, 128 KB
  h2* hbuf = (h2*)(smem + 131072);          // [2][128] h2 (256 halves per buffer)
  int b = blockIdx.x;
  int j = threadIdx.x;                      // 0..255

  h2 w0[96], w1[96], w2[96], w3[96];
  STAGE_ROW(w0, j)
  STAGE_ROW(w1, j + 256)
  STAGE_ROW(w2, j + 512)
  STAGE_ROW(w3, j + 768)
  if (j < 64) ((uint4*)hbuf)[j] = make_uint4(0, 0, 0, 0);
  float c = 0.0f;
  // preload Xw for t=0
  const float* xp0 = Xw + (size_t)(0 * 8 + b) * 1024 + j;
  float xwi = xp0[0], xwf = xp0[256], xwg = xp0[512], xwo = xp0[768];
  __syncthreads();

  const uint4* wr0 = wl + (size_t)j * 8;
  const uint4* wr1 = wl + (size_t)(j + 256) * 8;
  const uint4* wr2 = wl + (size_t)(j + 512) * 8;
  const uint4* wr3 = wl + (size_t)(j + 768) * 8;
  int sw = j & 7;

  for (int t = 0; t < 256; ++t) {
    // prefetch next step's Xw (hidden under this step's compute)
    float xni = 0, xnf = 0, xng = 0, xno = 0;
    if (t < 255) {
      const float* xp = Xw + (size_t)((t + 1) * 8 + b) * 1024 + j;
      xni = xp[0]; xnf = xp[256]; xng = xp[512]; xno = xp[768];
    }
    const uint4* hb = (const uint4*)(hbuf + (size_t)(t & 1) * 128);
    float a0 = 0.0f, a1 = 0.0f, a2 = 0.0f, a3 = 0.0f;
#pragma unroll
    for (int u = 0; u < 24; ++u) {  // cols 0..191 from registers
      uint4 hv = hb[u];
      h2 hx = bch2(hv.x), hy = bch2(hv.y), hz = bch2(hv.z), hw = bch2(hv.w);
      a0 = fdot2f(w0[4 * u], hx, a0); a0 = fdot2f(w0[4 * u + 1], hy, a0);
      a0 = fdot2f(w0[4 * u + 2], hz, a0); a0 = fdot2f(w0[4 * u + 3], hw, a0);
      a1 = fdot2f(w1[4 * u], hx, a1); a1 = fdot2f(w1[4 * u + 1], hy, a1);
      a1 = fdot2f(w1[4 * u + 2], hz, a1); a1 = fdot2f(w1[4 * u + 3], hw, a1);
      a2 = fdot2f(w2[4 * u], hx, a2); a2 = fdot2f(w2[4 * u + 1], hy, a2);
      a2 = fdot2f(w2[4 * u + 2], hz, a2); a2 = fdot2f(w2[4 * u + 3], hw, a2);
      a3 = fdot2f(w3[4 * u], hx, a3); a3 = fdot2f(w3[4 * u + 1], hy, a3);
      a3 = fdot2f(w3[4 * u + 2], hz, a3); a3 = fdot2f(w3[4 * u + 3], hw, a3);
    }
#pragma unroll
    for (int cb = 0; cb < 8; ++cb) {  // cols 192..255 from swizzled LDS
      uint4 hv = hb[24 + cb];
      h2 hx = bch2(hv.x), hy = bch2(hv.y), hz = bch2(hv.z), hw = bch2(hv.w);
      int sc = cb ^ sw;
      uint4 u0 = wr0[sc], u1 = wr1[sc], u2 = wr2[sc], u3 = wr3[sc];
      a0 = fdot2f(bch2(u0.x), hx, a0); a0 = fdot2f(bch2(u0.y), hy, a0);
      a0 = fdot2f(bch2(u0.z), hz, a0); a0 = fdot2f(bch2(u0.w), hw, a0);
      a1 = fdot2f(bch2(u1.x), hx, a1); a1 = fdot2f(bch2(u1.y), hy, a1);
      a1 = fdot2f(bch2(u1.z), hz, a1); a1 = fdot2f(bch2(u1.w), hw, a1);
      a2 = fdot2f(bch2(u2.x), hx, a2); a2 = fdot2f(bch2(u2.y), hy, a2);
      a2 = fdot2f(bch2(u2.z), hz, a2); a2 = fdot2f(bch2(u2.w), hw, a2);
      a3 = fdot2f(bch2(u3.x), hx, a3); a3 = fdot2f(bch2(u3.y), hy, a3);
      a3 = fdot2f(bch2(u3.z), hz, a3); a3 = fdot2f(bch2(u3.w), hw, a3);
    }
    float gi = a0 + xwi, gf = a1 + xwf, gg = a2 + xwg, go = a3 + xwo;
    c = sigf(gf) * c + sigf(gi) * tanhfast(gg);
    float hv_ = sigf(go) * tanhfast(c);
    _Float16* hn = (_Float16*)(hbuf + (size_t)((t + 1) & 1) * 128);
    hn[j] = (_Float16)hv_;
    dec_out[((size_t)(b * 256 + t)) * 256 + j] = hv_;
    __syncthreads();
    xwi = xni; xwf = xnf; xwg = xng; xwo = xno;
  }
}

// ---------------- pen transpose ----------------
__global__ void transpose_pen(const float* __restrict__ pen, float* __restrict__ penT) {
  int bx = blockIdx.x;
  int b = bx >> 8, h = bx & 255;
  int i = threadIdx.x;  // 256
  penT[(size_t)bx * 256 + i] = pen[((size_t)(b * 256 + i)) * 256 + h];
}

// ---------------- pointer logits ----------------
__global__ void pointer_kernel(const float* __restrict__ pd, const float* __restrict__ penT,
                               const float* __restrict__ vptr, float* __restrict__ out) {
  __shared__ float pdr[256];
  __shared__ float vl[256];
  int bx = blockIdx.x;
  int b = bx >> 8;
  int tid = threadIdx.x;  // 256
  pdr[tid] = pd[(size_t)bx * 256 + tid];
  vl[tid] = vptr[tid];
  __syncthreads();
  const float* pT = penT + (size_t)b * 256 * 256;
  float acc = 0.0f;
  for (int h = 0; h < 256; ++h) {
    acc = fmaf(vl[h], tanhfast(pdr[h] + pT[(size_t)h * 256 + tid]), acc);
  }
  out[(size_t)bx * 256 + tid] = acc;
}

extern "C" void kernel_launch(void* const* d_in, const int* in_sizes, int n_in,
                              void* d_out, int out_size, void* d_ws, size_t ws_size,
                              hipStream_t stream) {
  const float* parts = (const float*)d_in[0];
  const int* ts = (const int*)d_in[1];
  const float* Wpe1 = (const float*)d_in[2];
  const float* bpe1 = (const float*)d_in[3];
  const float* Wpe2 = (const float*)d_in[4];
  const float* bpe2 = (const float*)d_in[5];
  const float* pos = (const float*)d_in[6];
  const float* Wqkv = (const float*)d_in[7];
  const float* bqkv = (const float*)d_in[8];
  const float* Wo = (const float*)d_in[9];
  const float* bo = (const float*)d_in[10];
  const float* ln1g = (const float*)d_in[11];
  const float* ln1b = (const float*)d_in[12];
  const float* W1f = (const float*)d_in[13];
  const float* b1f = (const float*)d_in[14];
  const float* W2f = (const float*)d_in[15];
  const float* b2f = (const float*)d_in[16];
  const float* ln2g = (const float*)d_in[17];
  const float* ln2b = (const float*)d_in[18];
  const float* Wih = (const float*)d_in[19];
  const float* Whh = (const float*)d_in[20];
  const float* bih = (const float*)d_in[21];
  const float* bhh = (const float*)d_in[22];
  const float* Wp = (const float*)d_in[23];
  const float* bp = (const float*)d_in[24];
  const float* vptr = (const float*)d_in[25];
  float* out = (float*)d_out;

  float* W = (float*)d_ws;
  float* xbuf = W;                    // [2048,256]
  float* qkvb = W + 524288;           // [2048,768]
  float* attb = W + 2097152;          // [2048,256]
  float* obuf = W + 2621440;          // [2048,256]
  float* ffb  = W + 3145728;          // [2048,512]
  float* dec_in = obuf;
  float* Xw = qkvb;                   // [2048,1024]
  float* dec_out = ffb;
  float* pdb  = W + 3670016;          // [2048,256]
  float* penb = W + 4194304;          // [2048,256]
  float* penTb = W + 4718592;         // [2048,256]

  const int attnLDS = (256 * 33 + 32 * 33 + 32 * 257) * 4;  // 70912 B
  const int scanLDS = 131072 + 1024;                        // 132096 B
  hipFuncSetAttribute((const void*)attn_kernel, hipFuncAttributeMaxDynamicSharedMemorySize, attnLDS);
  hipFuncSetAttribute((const void*)lstm_scan, hipFuncAttributeMaxDynamicSharedMemorySize, scanLDS);

  part_encoder<<<2048, 128, 0, stream>>>(parts, Wpe1, bpe1, Wpe2, bpe2, pos, xbuf);
  for (int l = 0; l < 3; ++l) {
    gemm_f32<0><<<dim3(12, 32), 256, 0, stream>>>(xbuf, Wqkv + (size_t)l * 768 * 256,
                                                  bqkv + l * 768, nullptr, qkvb, 768, 256);
    attn_kernel<<<dim3(8, 8, 8), 256, attnLDS, stream>>>(qkvb, attb);
    gemm_f32<0><<<dim3(4, 32), 256, 0, stream>>>(attb, Wo + (size_t)l * 65536,
                                                 bo + l * 256, nullptr, obuf, 256, 256);
    ln_residual<<<2048, 256, 0, stream>>>(xbuf, obuf, ln1g + l * 256, ln1b + l * 256);
    gemm_f32<1><<<dim3(8, 32), 256, 0, stream>>>(xbuf, W1f + (size_t)l * 512 * 256,
                                                 b1f + l * 512, nullptr, ffb, 512, 256);
    gemm_f32<0><<<dim3(4, 32), 256, 0, stream>>>(ffb, W2f + (size_t)l * 256 * 512,
                                                 b2f + l * 256, nullptr, obuf, 256, 512);
    ln_residual<<<2048, 256, 0, stream>>>(xbuf, obuf, ln2g + l * 256, ln2b + l * 256);
  }
  gather_dec_in<<<2048, 64, 0, stream>>>(xbuf, ts, dec_in);
  gemm_f32<0><<<dim3(16, 32), 256, 0, stream>>>(dec_in, Wih, bih, bhh, Xw, 1024, 256);
  lstm_scan<<<8, 256, scanLDS, stream>>>(Xw, Whh, dec_out);
  gemm_f32<0><<<dim3(4, 32), 256, 0, stream>>>(dec_out, Wp, bp, nullptr, pdb, 256, 256);
  gemm_f32<0><<<dim3(4, 32), 256, 0, stream>>>(xbuf, Wp, bp, nullptr, penb, 256, 256);
  transpose_pen<<<2048, 256, 0, stream>>>(penb, penTb);
  pointer_kernel<<<2048, 256, 0, stream>>>(pdb, penTb, vptr, out);
}